// Round 2
// baseline (581.912 us; speedup 1.0000x reference)
//
#include <hip/hip_runtime.h>
#include <math.h>
#include <stdint.h>

// TDGSPooling2d: gumbel-softmax hard 2x2 pool, K=2, stride 2.
// x: (32,128,112,112) f32, temperature: (128,56,56) f32 -> out (32,128,56,56) f32
// Forward == x_patch[argmax_j softmax(x_j/T + gumbel_j)] (hard straight-through).
// Gumbel noise must be BIT-EXACT vs jax.random.uniform(key(42), shape):
// threefry2x32 partitionable layout, 32-bit draw i is
//   bits[i] = out0 ^ out1 of threefry2x32(key=(0,42), ctr=(hi32(i), lo32(i)))
// (for bit_width<64 JAX XORs the two output words — _threefry_random_bits_partitionable).

__device__ __forceinline__ uint32_t rotl32(uint32_t x, int d) {
    return (x << d) | (x >> (32 - d));
}

// threefry2x32 with key (0, 42); returns xor of the two output words.
__device__ __forceinline__ uint32_t tf_xor(uint32_t x0, uint32_t x1) {
    const uint32_t ks0 = 0u;
    const uint32_t ks1 = 42u;
    const uint32_t ks2 = 0x1BD11BDAu ^ ks0 ^ ks1;
    x0 += ks0; x1 += ks1;
#define TFR(r) { x0 += x1; x1 = rotl32(x1, (r)); x1 ^= x0; }
    TFR(13) TFR(15) TFR(26) TFR(6)
    x0 += ks1; x1 += ks2 + 1u;
    TFR(17) TFR(29) TFR(16) TFR(24)
    x0 += ks2; x1 += ks0 + 2u;
    TFR(13) TFR(15) TFR(26) TFR(6)
    x0 += ks0; x1 += ks1 + 3u;
    TFR(17) TFR(29) TFR(16) TFR(24)
    x0 += ks1; x1 += ks2 + 4u;
    TFR(13) TFR(15) TFR(26) TFR(6)
    x0 += ks2; x1 += ks0 + 5u;
#undef TFR
    return x0 ^ x1;
}

__global__ __launch_bounds__(256) void tdgs_pool_kernel(
    const float* __restrict__ x,
    const float* __restrict__ temperature,
    float* __restrict__ out,
    int total)
{
    int n = blockIdx.x * 256 + threadIdx.x;
    if (n >= total) return;

    // n = ((b*128 + c)*56 + h)*56 + w  (row-major over (B,C,Ho,Wo))
    int w  = n % 56;
    int t  = n / 56;
    int h  = t % 56;
    int t2 = t / 56;
    int c  = t2 % 128;
    int b  = t2 / 128;

    // temps = relu(temperature) + 0.1 (f32, same op order as reference)
    float T = fmaxf(temperature[(c * 56 + h) * 56 + w], 0.0f) + 0.1f;

    // 2x2 patch, row-major within patch: [ (2h,2w), (2h,2w+1), (2h+1,2w), (2h+1,2w+1) ]
    const float* xr = x + ((size_t)(b * 128 + c) * 112 + 2 * h) * 112 + 2 * w;
    float2 r0 = *(const float2*)(xr);
    float2 r1 = *(const float2*)(xr + 112);
    float pv[4] = {r0.x, r0.y, r1.x, r1.y};

    // Gumbel noise: flat element index i = n*4 + j over (B,C,Ho,Wo,4); i < 2^32
    uint32_t base = (uint32_t)n * 4u;
    float z[4];
#pragma unroll
    for (int j = 0; j < 4; ++j) {
        uint32_t bits = tf_xor(0u, base + (uint32_t)j);
        // jax _uniform: floats = bitcast(bits>>9 | 0x3f800000) - 1.0
        //               u = max(minval, floats*(maxval-minval) + minval)
        float f = __uint_as_float((bits >> 9) | 0x3f800000u) - 1.0f;
        float u = fmaxf(f + 1e-20f, 1e-20f); // (maxval-minval) == 1.0f in f32
        // g = -log(-log(u)); each log correctly rounded to f32 via f64
        float t1 = (float)log((double)u);
        float t3 = (float)log((double)(-t1));
        float g = -t3;
        // logits = x/T (IEEE f32 div), z = logits + g
        z[j] = pv[j] / T + g;
    }

    // Emulate jax.nn.softmax + first-occurrence argmax in f32
    float m = fmaxf(fmaxf(z[0], z[1]), fmaxf(z[2], z[3]));
    float e0 = (float)exp((double)(z[0] - m));
    float e1 = (float)exp((double)(z[1] - m));
    float e2 = (float)exp((double)(z[2] - m));
    float e3 = (float)exp((double)(z[3] - m));
    float s = ((e0 + e1) + e2) + e3;
    float s0 = e0 / s, s1 = e1 / s, s2 = e2 / s, s3 = e3 / s;

    int best = 0;
    float bv = s0;
    if (s1 > bv) { bv = s1; best = 1; }
    if (s2 > bv) { bv = s2; best = 2; }
    if (s3 > bv) { bv = s3; best = 3; }

    out[n] = pv[best];
}

extern "C" void kernel_launch(void* const* d_in, const int* in_sizes, int n_in,
                              void* d_out, int out_size, void* d_ws, size_t ws_size,
                              hipStream_t stream) {
    const float* x    = (const float*)d_in[0];
    const float* temp = (const float*)d_in[1];
    float* out = (float*)d_out;

    int total = out_size; // 32*128*56*56 = 12,845,056
    int blocks = (total + 255) / 256; // 50176
    tdgs_pool_kernel<<<blocks, 256, 0, stream>>>(x, temp, out, total);
}

// Round 3
// 432.869 us; speedup vs baseline: 1.3443x; 1.3443x over previous
//
#include <hip/hip_runtime.h>
#include <math.h>
#include <stdint.h>

// TDGSPooling2d: gumbel-softmax hard 2x2 pool, K=2, stride 2.
// x: (32,128,112,112) f32, temperature: (128,56,56) f32 -> out (32,128,56,56) f32
// Forward == x_patch[argmax_j softmax(x_j/T + gumbel_j)] (hard straight-through).
// Gumbel noise BIT-EXACT vs jax.random.uniform(key(42), shape):
//   bits[i] = out0 ^ out1 of threefry2x32(key=(0,42), ctr=(0, i))  [partitionable]
//
// R2->R3: replaced libm double log/exp (≈90 f64 ops each, ~2200 slots/pixel)
// with branch-free ~2^-44-accurate f64 routines (~16 f64 ops each). f32-rounded
// results differ from libm with prob ~2^-20/call; an argmax flip additionally
// needs a ~2^-24 z-near-tie -> expected flips << 1e-3 over all pixels.

__device__ __forceinline__ uint32_t rotl32(uint32_t x, int d) {
    return (x << d) | (x >> (32 - d));
}

// threefry2x32 with key (0, 42); returns xor of the two output words.
__device__ __forceinline__ uint32_t tf_xor(uint32_t x0, uint32_t x1) {
    const uint32_t ks0 = 0u;
    const uint32_t ks1 = 42u;
    const uint32_t ks2 = 0x1BD11BDAu ^ ks0 ^ ks1;
    x0 += ks0; x1 += ks1;
#define TFR(r) { x0 += x1; x1 = rotl32(x1, (r)); x1 ^= x0; }
    TFR(13) TFR(15) TFR(26) TFR(6)
    x0 += ks1; x1 += ks2 + 1u;
    TFR(17) TFR(29) TFR(16) TFR(24)
    x0 += ks2; x1 += ks0 + 2u;
    TFR(13) TFR(15) TFR(26) TFR(6)
    x0 += ks0; x1 += ks1 + 3u;
    TFR(17) TFR(29) TFR(16) TFR(24)
    x0 += ks1; x1 += ks2 + 4u;
    TFR(13) TFR(15) TFR(26) TFR(6)
    x0 += ks2; x1 += ks0 + 5u;
#undef TFR
    return x0 ^ x1;
}

// ~0.5-ulp f64 reciprocal: v_rcp_f64 (+2 Newton). Fallback: IEEE div.
__device__ __forceinline__ double drcp(double b) {
#if __has_builtin(__builtin_amdgcn_rcp)
    double r = __builtin_amdgcn_rcp(b);
    r = __builtin_fma(__builtin_fma(-b, r, 1.0), r, r);
    r = __builtin_fma(__builtin_fma(-b, r, 1.0), r, r);
    return r;
#else
    return 1.0 / b;
#endif
}

// ln(uf) for positive normal f32, computed in f64 with ~2^-44 rel error,
// rounded to f32 (matches CR-f32 except ~2^-20 of inputs, by 1 ulp).
__device__ __forceinline__ float flog_cr(float uf) {
    uint32_t ib = __float_as_uint(uf);
    int ex = (int)(ib >> 23) - 127;
    uint32_t mant = ib & 0x7FFFFFu;
    int up = (mant > 0x3504F3u) ? 1 : 0;   // m > sqrt(2) -> halve, e+1
    int e = ex + up;
    // build double m in [sqrt2/2, sqrt2] with the f32 mantissa (exact)
    uint64_t dbits = ((uint64_t)mant << 29) | ((uint64_t)(1023 - up) << 52);
    double m = __longlong_as_double((long long)dbits);
    // s = (m-1)/(m+1); m+1, m-1 exact
    double r = drcp(m + 1.0);
    double s = (m - 1.0) * r;
    double q = s * s;                       // q <= 0.02944
    // 2*atanh(s) = s*(2 + q*(2/3 + q*(2/5 + ... + q*(2/15))))
    double p = 2.0 / 15.0;
    p = __builtin_fma(p, q, 2.0 / 13.0);
    p = __builtin_fma(p, q, 2.0 / 11.0);
    p = __builtin_fma(p, q, 2.0 / 9.0);
    p = __builtin_fma(p, q, 2.0 / 7.0);
    p = __builtin_fma(p, q, 2.0 / 5.0);
    p = __builtin_fma(p, q, 2.0 / 3.0);
    p = __builtin_fma(p, q, 2.0);
    double ln = __builtin_fma((double)e, 0x1.62e42fefa39efp-1, s * p);
    return (float)ln;
}

// exp(df) for f32 df in [-46, 0], f64 with ~2^-49 rel error, rounded to f32.
__device__ __forceinline__ float fexp_cr(float df) {
    double d = (double)df;
    double kd = __builtin_rint(d * 0x1.71547652b82fep+0);   // round(d*log2e)
    double r = __builtin_fma(kd, -0x1.62e42fefa39efp-1, d); // d - k*ln2_hi
    r = __builtin_fma(kd, -0x1.abc9e3b39803fp-56, r);       //   - k*ln2_lo
    // exp(r), |r| <= 0.3466, degree-11 Taylor (trunc 2^-47 rel)
    double p = 1.0 / 39916800.0;
    p = __builtin_fma(p, r, 1.0 / 3628800.0);
    p = __builtin_fma(p, r, 1.0 / 362880.0);
    p = __builtin_fma(p, r, 1.0 / 40320.0);
    p = __builtin_fma(p, r, 1.0 / 5040.0);
    p = __builtin_fma(p, r, 1.0 / 720.0);
    p = __builtin_fma(p, r, 1.0 / 120.0);
    p = __builtin_fma(p, r, 1.0 / 24.0);
    p = __builtin_fma(p, r, 1.0 / 6.0);
    p = __builtin_fma(p, r, 0.5);
    p = __builtin_fma(p, r, 1.0);
    p = __builtin_fma(p, r, 1.0);
    // scale by 2^k via exponent-field add (k in [-45,0], no denormal risk)
    long long nb = (long long)(int)kd;
    double ev = __longlong_as_double(__double_as_longlong(p) + (nb << 52));
    return (float)ev;
}

__global__ __launch_bounds__(256) void tdgs_pool_kernel(
    const float* __restrict__ x,
    const float* __restrict__ temperature,
    float* __restrict__ out,
    int total)
{
    int n = blockIdx.x * 256 + threadIdx.x;
    if (n >= total) return;

    // n = ((b*128 + c)*56 + h)*56 + w  (row-major over (B,C,Ho,Wo))
    int w  = n % 56;
    int t  = n / 56;
    int h  = t % 56;
    int t2 = t / 56;
    int c  = t2 % 128;
    int b  = t2 / 128;

    // temps = relu(temperature) + 0.1 (f32, same op order as reference)
    float T = fmaxf(temperature[(c * 56 + h) * 56 + w], 0.0f) + 0.1f;

    // 2x2 patch, row-major within patch
    const float* xr = x + ((size_t)(b * 128 + c) * 112 + 2 * h) * 112 + 2 * w;
    float2 r0 = *(const float2*)(xr);
    float2 r1 = *(const float2*)(xr + 112);
    float pv[4] = {r0.x, r0.y, r1.x, r1.y};

    // Gumbel noise: flat element index i = n*4 + j over (B,C,Ho,Wo,4); i < 2^32
    uint32_t base = (uint32_t)n * 4u;
    float z[4];
#pragma unroll
    for (int j = 0; j < 4; ++j) {
        uint32_t bits = tf_xor(0u, base + (uint32_t)j);
        // jax _uniform: f = bitcast(bits>>9 | 0x3f800000) - 1.0; u = max(f+lo, lo)
        float f = __uint_as_float((bits >> 9) | 0x3f800000u) - 1.0f;
        float u = fmaxf(f + 1e-20f, 1e-20f);
        float t1 = flog_cr(u);        // ln u  (f32-rounded)
        float g  = -flog_cr(-t1);     // -ln(-ln u)
        // logits = x/T (IEEE f32 div), z = logits + g
        z[j] = pv[j] / T + g;
    }

    // Emulate jax.nn.softmax + first-occurrence argmax in f32
    float m = fmaxf(fmaxf(z[0], z[1]), fmaxf(z[2], z[3]));
    float e0 = fexp_cr(z[0] - m);
    float e1 = fexp_cr(z[1] - m);
    float e2 = fexp_cr(z[2] - m);
    float e3 = fexp_cr(z[3] - m);
    float s = ((e0 + e1) + e2) + e3;
    float s0 = e0 / s, s1 = e1 / s, s2 = e2 / s, s3 = e3 / s;

    int best = 0;
    float bv = s0;
    if (s1 > bv) { bv = s1; best = 1; }
    if (s2 > bv) { bv = s2; best = 2; }
    if (s3 > bv) { bv = s3; best = 3; }

    out[n] = pv[best];
}

extern "C" void kernel_launch(void* const* d_in, const int* in_sizes, int n_in,
                              void* d_out, int out_size, void* d_ws, size_t ws_size,
                              hipStream_t stream) {
    const float* x    = (const float*)d_in[0];
    const float* temp = (const float*)d_in[1];
    float* out = (float*)d_out;

    int total = out_size; // 32*128*56*56 = 12,845,056
    int blocks = (total + 255) / 256; // 50176
    tdgs_pool_kernel<<<blocks, 256, 0, stream>>>(x, temp, out, total);
}

// Round 4
// 350.095 us; speedup vs baseline: 1.6622x; 1.2364x over previous
//
#include <hip/hip_runtime.h>
#include <math.h>
#include <stdint.h>

// TDGSPooling2d: gumbel-softmax hard 2x2 pool, K=2, stride 2.
// x: (32,128,112,112) f32, temperature: (128,56,56) f32 -> out (32,128,56,56) f32
// Forward == x_patch[argmax_j softmax(x_j/T + gumbel_j)] (hard straight-through).
// Gumbel noise BIT-EXACT vs jax.random.uniform(key(42), shape):
//   bits[i] = out0 ^ out1 of threefry2x32(key=(0,42), ctr=(0, i))  [partitionable]
//
// R3->R4: two-tier precision. Fast path computes z with an all-f32 log chain
// (err(g) <= ~1e-5) and takes argmax(z) directly -- valid because
// argmax(softmax(z)) == argmax(z) unless the top-2 z gap is ~2^-22 (exp/div
// rounding collapse). Fallback to the bit-faithful f64 emulation only when
// the approximate top-2 gap < 2^-12 (~5e-4 of pixels), which covers both the
// fast-path error (2*eps ~ 6e-5) and all collapse scales with 4x margin.

__device__ __forceinline__ uint32_t rotl32(uint32_t x, int d) {
    return (x << d) | (x >> (32 - d));
}

// threefry2x32 with key (0, 42); returns xor of the two output words.
__device__ __forceinline__ uint32_t tf_xor(uint32_t x0, uint32_t x1) {
    const uint32_t ks0 = 0u;
    const uint32_t ks1 = 42u;
    const uint32_t ks2 = 0x1BD11BDAu ^ ks0 ^ ks1;
    x0 += ks0; x1 += ks1;
#define TFR(r) { x0 += x1; x1 = rotl32(x1, (r)); x1 ^= x0; }
    TFR(13) TFR(15) TFR(26) TFR(6)
    x0 += ks1; x1 += ks2 + 1u;
    TFR(17) TFR(29) TFR(16) TFR(24)
    x0 += ks2; x1 += ks0 + 2u;
    TFR(13) TFR(15) TFR(26) TFR(6)
    x0 += ks0; x1 += ks1 + 3u;
    TFR(17) TFR(29) TFR(16) TFR(24)
    x0 += ks1; x1 += ks2 + 4u;
    TFR(13) TFR(15) TFR(26) TFR(6)
    x0 += ks2; x1 += ks0 + 5u;
#undef TFR
    return x0 ^ x1;
}

// ---------- fast f32 path (decision only; ~1.5 ulp rel error) ----------

// ln(uf), positive normal f32, all-f32, rel err ~2^-21.
__device__ __forceinline__ float flog_fast(float uf) {
    uint32_t ib = __float_as_uint(uf);
    int ex = (int)(ib >> 23) - 127;
    uint32_t mant = ib & 0x7FFFFFu;
    uint32_t up = (mant > 0x3504F3u) ? 1u : 0u;   // m > sqrt(2) -> halve, e+1
    float e = (float)(ex + (int)up);
    float m = __uint_as_float(mant | ((127u - up) << 23)); // [sqrt2/2, sqrt2]
    // s = (m-1)/(m+1) via v_rcp_f32 (1 ulp); |s| <= 0.1716
    float r = __builtin_amdgcn_rcpf(m + 1.0f);
    float s = (m - 1.0f) * r;
    float q = s * s;                                // q <= 0.0295
    float p = 0.22222222f;                          // 2/9
    p = __builtin_fmaf(p, q, 0.28571429f);          // 2/7
    p = __builtin_fmaf(p, q, 0.4f);                 // 2/5
    p = __builtin_fmaf(p, q, 0.66666667f);          // 2/3
    p = __builtin_fmaf(p, q, 2.0f);
    return __builtin_fmaf(e, 0.69314718f, s * p);
}

// ---------- precise f64 fallback (bit-faithful vs R3 / libm-f32) ----------

__device__ __forceinline__ double drcp(double b) {
#if __has_builtin(__builtin_amdgcn_rcp)
    double r = __builtin_amdgcn_rcp(b);
    r = __builtin_fma(__builtin_fma(-b, r, 1.0), r, r);
    r = __builtin_fma(__builtin_fma(-b, r, 1.0), r, r);
    return r;
#else
    return 1.0 / b;
#endif
}

__device__ __forceinline__ float flog_cr(float uf) {
    uint32_t ib = __float_as_uint(uf);
    int ex = (int)(ib >> 23) - 127;
    uint32_t mant = ib & 0x7FFFFFu;
    int up = (mant > 0x3504F3u) ? 1 : 0;
    int e = ex + up;
    uint64_t dbits = ((uint64_t)mant << 29) | ((uint64_t)(1023 - up) << 52);
    double m = __longlong_as_double((long long)dbits);
    double r = drcp(m + 1.0);
    double s = (m - 1.0) * r;
    double q = s * s;
    double p = 2.0 / 15.0;
    p = __builtin_fma(p, q, 2.0 / 13.0);
    p = __builtin_fma(p, q, 2.0 / 11.0);
    p = __builtin_fma(p, q, 2.0 / 9.0);
    p = __builtin_fma(p, q, 2.0 / 7.0);
    p = __builtin_fma(p, q, 2.0 / 5.0);
    p = __builtin_fma(p, q, 2.0 / 3.0);
    p = __builtin_fma(p, q, 2.0);
    double ln = __builtin_fma((double)e, 0x1.62e42fefa39efp-1, s * p);
    return (float)ln;
}

__device__ __forceinline__ float fexp_cr(float df) {
    double d = (double)df;
    double kd = __builtin_rint(d * 0x1.71547652b82fep+0);
    double r = __builtin_fma(kd, -0x1.62e42fefa39efp-1, d);
    r = __builtin_fma(kd, -0x1.abc9e3b39803fp-56, r);
    double p = 1.0 / 39916800.0;
    p = __builtin_fma(p, r, 1.0 / 3628800.0);
    p = __builtin_fma(p, r, 1.0 / 362880.0);
    p = __builtin_fma(p, r, 1.0 / 40320.0);
    p = __builtin_fma(p, r, 1.0 / 5040.0);
    p = __builtin_fma(p, r, 1.0 / 720.0);
    p = __builtin_fma(p, r, 1.0 / 120.0);
    p = __builtin_fma(p, r, 1.0 / 24.0);
    p = __builtin_fma(p, r, 1.0 / 6.0);
    p = __builtin_fma(p, r, 0.5);
    p = __builtin_fma(p, r, 1.0);
    p = __builtin_fma(p, r, 1.0);
    long long nb = (long long)(int)kd;
    double ev = __longlong_as_double(__double_as_longlong(p) + (nb << 52));
    return (float)ev;
}

__global__ __launch_bounds__(256) void tdgs_pool_kernel(
    const float* __restrict__ x,
    const float* __restrict__ temperature,
    float* __restrict__ out,
    int total)
{
    int n = blockIdx.x * 256 + threadIdx.x;
    if (n >= total) return;

    int w  = n % 56;
    int t  = n / 56;
    int h  = t % 56;
    int t2 = t / 56;
    int c  = t2 % 128;
    int b  = t2 / 128;

    float T = fmaxf(temperature[(c * 56 + h) * 56 + w], 0.0f) + 0.1f;

    const float* xr = x + ((size_t)(b * 128 + c) * 112 + 2 * h) * 112 + 2 * w;
    float2 r0 = *(const float2*)(xr);
    float2 r1 = *(const float2*)(xr + 112);
    float pv[4] = {r0.x, r0.y, r1.x, r1.y};

    uint32_t base = (uint32_t)n * 4u;
    float uu[4];
#pragma unroll
    for (int j = 0; j < 4; ++j) {
        uint32_t bits = tf_xor(0u, base + (uint32_t)j);
        float f = __uint_as_float((bits >> 9) | 0x3f800000u) - 1.0f;
        uu[j] = fmaxf(f + 1e-20f, 1e-20f);
    }

    // ---- fast path: approximate z, argmax + top-2 margin ----
    float rT = __builtin_amdgcn_rcpf(T);   // ~1 ulp; error covered by theta
    float z[4];
#pragma unroll
    for (int j = 0; j < 4; ++j) {
        float l1 = flog_fast(uu[j]);
        float g  = -flog_fast(-l1);
        z[j] = __builtin_fmaf(pv[j], rT, g);
    }

    // top-2: max and second-max of 4
    float a0 = fmaxf(z[0], z[1]), b0 = fminf(z[0], z[1]);
    float a1 = fmaxf(z[2], z[3]), b1 = fminf(z[2], z[3]);
    float m1 = fmaxf(a0, a1);
    float m2 = fmaxf(fminf(a0, a1), fmaxf(b0, b1));

    int best = 0;
    float bv = z[0];
    if (z[1] > bv) { bv = z[1]; best = 1; }
    if (z[2] > bv) { bv = z[2]; best = 2; }
    if (z[3] > bv) { bv = z[3]; best = 3; }

    const float THETA = 2.44140625e-4f;    // 2^-12
    if (__builtin_expect(m1 - m2 < THETA, 0)) {
        // ---- precise fallback: bit-faithful f32 emulation via f64 ----
        float zp[4];
#pragma unroll
        for (int j = 0; j < 4; ++j) {
            float t1 = flog_cr(uu[j]);
            float g  = -flog_cr(-t1);
            zp[j] = pv[j] / T + g;      // IEEE f32 div, as reference
        }
        float mm = fmaxf(fmaxf(zp[0], zp[1]), fmaxf(zp[2], zp[3]));
        float e0 = fexp_cr(zp[0] - mm);
        float e1 = fexp_cr(zp[1] - mm);
        float e2 = fexp_cr(zp[2] - mm);
        float e3 = fexp_cr(zp[3] - mm);
        float s = ((e0 + e1) + e2) + e3;
        float s0 = e0 / s, s1 = e1 / s, s2 = e2 / s, s3 = e3 / s;
        best = 0;
        float bvp = s0;
        if (s1 > bvp) { bvp = s1; best = 1; }
        if (s2 > bvp) { bvp = s2; best = 2; }
        if (s3 > bvp) { bvp = s3; best = 3; }
    }

    out[n] = pv[best];
}

extern "C" void kernel_launch(void* const* d_in, const int* in_sizes, int n_in,
                              void* d_out, int out_size, void* d_ws, size_t ws_size,
                              hipStream_t stream) {
    const float* x    = (const float*)d_in[0];
    const float* temp = (const float*)d_in[1];
    float* out = (float*)d_out;

    int total = out_size; // 32*128*56*56 = 12,845,056
    int blocks = (total + 255) / 256; // 50176
    tdgs_pool_kernel<<<blocks, 256, 0, stream>>>(x, temp, out, total);
}

// Round 5
// 330.522 us; speedup vs baseline: 1.7606x; 1.0592x over previous
//
#include <hip/hip_runtime.h>
#include <math.h>
#include <stdint.h>

// TDGSPooling2d: gumbel-softmax hard 2x2 pool, K=2, stride 2.
// x: (32,128,112,112) f32, temperature: (128,56,56) f32 -> out (32,128,56,56) f32
// Forward == x_patch[argmax_j softmax(x_j/T + gumbel_j)] (hard straight-through).
// Gumbel noise BIT-EXACT vs jax.random.uniform(key(42), shape):
//   bits[i] = out0 ^ out1 of threefry2x32(key=(0,42), ctr=(0, i))  [partitionable]
//
// R4->R5: (a) fast-path logs via HW v_log_f32 (quarter-rate) with a log1p
// series guard for u > 1-2^-6 (HW log2 has ~2^-22 ABS error near 1; the tiny
// first-log output would be relatively wrong and the second log amplifies it
// past theta). Elsewhere |log2 u| >= 0.0227 caps amplification at ~1.1e-5.
// Total fast-z error <= ~3e-5 << theta/2 = 1.2e-4 -> decisions identical.
// (b) 2 pixels/thread: float4 x loads, float2 temp/out, decode amortized.

__device__ __forceinline__ uint32_t rotl32(uint32_t x, int d) {
    return (x << d) | (x >> (32 - d));
}

// threefry2x32 with key (0, 42); returns xor of the two output words.
__device__ __forceinline__ uint32_t tf_xor(uint32_t x0, uint32_t x1) {
    const uint32_t ks0 = 0u;
    const uint32_t ks1 = 42u;
    const uint32_t ks2 = 0x1BD11BDAu ^ ks0 ^ ks1;
    x0 += ks0; x1 += ks1;
#define TFR(r) { x0 += x1; x1 = rotl32(x1, (r)); x1 ^= x0; }
    TFR(13) TFR(15) TFR(26) TFR(6)
    x0 += ks1; x1 += ks2 + 1u;
    TFR(17) TFR(29) TFR(16) TFR(24)
    x0 += ks2; x1 += ks0 + 2u;
    TFR(13) TFR(15) TFR(26) TFR(6)
    x0 += ks0; x1 += ks1 + 3u;
    TFR(17) TFR(29) TFR(16) TFR(24)
    x0 += ks1; x1 += ks2 + 4u;
    TFR(13) TFR(15) TFR(26) TFR(6)
    x0 += ks2; x1 += ks0 + 5u;
#undef TFR
    return x0 ^ x1;
}

__device__ __forceinline__ float hwlog2(float x) {
#if __has_builtin(__builtin_amdgcn_logf)
    return __builtin_amdgcn_logf(x);   // v_log_f32 (log base 2)
#else
    return __log2f(x);
#endif
}

// ---------- precise f64 fallback (bit-faithful vs libm-f32 chain) ----------

__device__ __forceinline__ double drcp(double b) {
#if __has_builtin(__builtin_amdgcn_rcp)
    double r = __builtin_amdgcn_rcp(b);
    r = __builtin_fma(__builtin_fma(-b, r, 1.0), r, r);
    r = __builtin_fma(__builtin_fma(-b, r, 1.0), r, r);
    return r;
#else
    return 1.0 / b;
#endif
}

__device__ __forceinline__ float flog_cr(float uf) {
    uint32_t ib = __float_as_uint(uf);
    int ex = (int)(ib >> 23) - 127;
    uint32_t mant = ib & 0x7FFFFFu;
    int up = (mant > 0x3504F3u) ? 1 : 0;
    int e = ex + up;
    uint64_t dbits = ((uint64_t)mant << 29) | ((uint64_t)(1023 - up) << 52);
    double m = __longlong_as_double((long long)dbits);
    double r = drcp(m + 1.0);
    double s = (m - 1.0) * r;
    double q = s * s;
    double p = 2.0 / 15.0;
    p = __builtin_fma(p, q, 2.0 / 13.0);
    p = __builtin_fma(p, q, 2.0 / 11.0);
    p = __builtin_fma(p, q, 2.0 / 9.0);
    p = __builtin_fma(p, q, 2.0 / 7.0);
    p = __builtin_fma(p, q, 2.0 / 5.0);
    p = __builtin_fma(p, q, 2.0 / 3.0);
    p = __builtin_fma(p, q, 2.0);
    double ln = __builtin_fma((double)e, 0x1.62e42fefa39efp-1, s * p);
    return (float)ln;
}

__device__ __forceinline__ float fexp_cr(float df) {
    double d = (double)df;
    double kd = __builtin_rint(d * 0x1.71547652b82fep+0);
    double r = __builtin_fma(kd, -0x1.62e42fefa39efp-1, d);
    r = __builtin_fma(kd, -0x1.abc9e3b39803fp-56, r);
    double p = 1.0 / 39916800.0;
    p = __builtin_fma(p, r, 1.0 / 3628800.0);
    p = __builtin_fma(p, r, 1.0 / 362880.0);
    p = __builtin_fma(p, r, 1.0 / 40320.0);
    p = __builtin_fma(p, r, 1.0 / 5040.0);
    p = __builtin_fma(p, r, 1.0 / 720.0);
    p = __builtin_fma(p, r, 1.0 / 120.0);
    p = __builtin_fma(p, r, 1.0 / 24.0);
    p = __builtin_fma(p, r, 1.0 / 6.0);
    p = __builtin_fma(p, r, 0.5);
    p = __builtin_fma(p, r, 1.0);
    p = __builtin_fma(p, r, 1.0);
    long long nb = (long long)(int)kd;
    double ev = __longlong_as_double(__double_as_longlong(p) + (nb << 52));
    return (float)ev;
}

// Bit-faithful emulation of the reference chain; returns the pooled value.
__device__ __forceinline__ float precise_pick(const float* pv, const float* uu, float T) {
    float zp[4];
#pragma unroll
    for (int j = 0; j < 4; ++j) {
        float t1 = flog_cr(uu[j]);
        float g  = -flog_cr(-t1);
        zp[j] = pv[j] / T + g;          // IEEE f32 div, as reference
    }
    float mm = fmaxf(fmaxf(zp[0], zp[1]), fmaxf(zp[2], zp[3]));
    float e0 = fexp_cr(zp[0] - mm);
    float e1 = fexp_cr(zp[1] - mm);
    float e2 = fexp_cr(zp[2] - mm);
    float e3 = fexp_cr(zp[3] - mm);
    float s = ((e0 + e1) + e2) + e3;
    float s0 = e0 / s, s1 = e1 / s, s2 = e2 / s, s3 = e3 / s;
    float bv = s0, sel = pv[0];
    if (s1 > bv) { bv = s1; sel = pv[1]; }
    if (s2 > bv) { bv = s2; sel = pv[2]; }
    if (s3 > bv) { bv = s3; sel = pv[3]; }
    return sel;
}

__global__ __launch_bounds__(256) void tdgs_pool_kernel(
    const float* __restrict__ x,
    const float* __restrict__ temperature,
    float* __restrict__ out,
    int npairs)
{
    int np = blockIdx.x * 256 + threadIdx.x;
    if (np >= npairs) return;

    // pair index: out pixels n0=2*np, n0+1 (adjacent w). w = 2*w2, w2 in [0,28)
    int w2 = np % 28;
    int t  = np / 28;
    int h  = t % 56;
    int t2 = t / 56;
    int c  = t2 & 127;
    int b  = t2 >> 7;

    float2 tv = *(const float2*)(temperature + (c * 56 + h) * 56 + 2 * w2);
    float Ts[2] = { fmaxf(tv.x, 0.0f) + 0.1f, fmaxf(tv.y, 0.0f) + 0.1f };

    const float* xr = x + ((size_t)(b * 128 + c) * 112 + 2 * h) * 112 + 4 * w2;
    float4 r0 = *(const float4*)(xr);
    float4 r1 = *(const float4*)(xr + 112);
    float pv[2][4] = { { r0.x, r0.y, r1.x, r1.y },
                       { r0.z, r0.w, r1.z, r1.w } };

    // draws: pixel n uses counters 4n+j -> base = 8*np
    uint32_t base = (uint32_t)np * 8u;
    float uu[2][4];
#pragma unroll
    for (int k = 0; k < 8; ++k) {
        uint32_t bits = tf_xor(0u, base + (uint32_t)k);
        float f = __uint_as_float((bits >> 9) | 0x3f800000u) - 1.0f;
        uu[k >> 2][k & 3] = fmaxf(f + 1e-20f, 1e-20f);
    }

    float res[2];
#pragma unroll
    for (int p = 0; p < 2; ++p) {
        float rT = __builtin_amdgcn_rcpf(Ts[p]);   // decision only; error << theta
        float z[4];
#pragma unroll
        for (int j = 0; j < 4; ++j) {
            float u = uu[p][j];
            // ln(u): HW log2*ln2, except u>1-2^-6 -> log1p series (rel err <=5e-7)
            float l1h = hwlog2(u) * 0.69314718f;
            float d = u - 1.0f;                         // exact (Sterbenz)
            float pp = __builtin_fmaf(d, -0.25f, 0.33333333f);
            pp = __builtin_fmaf(d, pp, -0.5f);
            pp = __builtin_fmaf(d, pp, 1.0f);
            float l1n = d * pp;
            float l1 = (d > -0.015625f) ? l1n : l1h;
            // g = -ln(-l1) = log2(-l1) * (-ln2); second log safe near 1 (abs err)
            float g = hwlog2(-l1) * -0.69314718f;
            z[j] = __builtin_fmaf(pv[p][j], rT, g);
        }
        // top-2 margin
        float a0 = fmaxf(z[0], z[1]), b0 = fminf(z[0], z[1]);
        float a1 = fmaxf(z[2], z[3]), b1 = fminf(z[2], z[3]);
        float m1 = fmaxf(a0, a1);
        float m2 = fmaxf(fminf(a0, a1), fmaxf(b0, b1));

        float bv = z[0], sel = pv[p][0];
        if (z[1] > bv) { bv = z[1]; sel = pv[p][1]; }
        if (z[2] > bv) { bv = z[2]; sel = pv[p][2]; }
        if (z[3] > bv) { bv = z[3]; sel = pv[p][3]; }

        const float THETA = 2.44140625e-4f;    // 2^-12
        if (__builtin_expect(m1 - m2 < THETA, 0)) {
            sel = precise_pick(pv[p], uu[p], Ts[p]);
        }
        res[p] = sel;
    }

    float2 o; o.x = res[0]; o.y = res[1];
    *(float2*)(out + (size_t)np * 2) = o;
}

extern "C" void kernel_launch(void* const* d_in, const int* in_sizes, int n_in,
                              void* d_out, int out_size, void* d_ws, size_t ws_size,
                              hipStream_t stream) {
    const float* x    = (const float*)d_in[0];
    const float* temp = (const float*)d_in[1];
    float* out = (float*)d_out;

    int npairs = out_size / 2;                 // 6,422,528
    int blocks = (npairs + 255) / 256;         // 25088
    tdgs_pool_kernel<<<blocks, 256, 0, stream>>>(x, temp, out, npairs);
}